// Round 11
// baseline (85.775 us; speedup 1.0000x reference)
//
#include <hip/hip_runtime.h>
#include <math.h>

// Shapes: x:(64,196,768) f32, ln_w/ln_b:(768,), sw/sb:(196,2,196), dw:(196,2)
//   W[o,n] = sum_m dw[o,m]*sw[o,m,n];  c[o] = sum_m dw[o,m]*sum_n sb[o,m,n]
//   t[b,o,d] = ln_w[d]*sum_n W[o,n]*xh[b,n,d] + ln_b[d]*rowsum[o] + c[o]
//   out[b,o,d] = x[b,o,d] * (gelu_erf(t) + 1)
// bf16 split MFMA: acc += Whi*Bhi + Whi*Blo + Wlo*Bhi (lo*lo dropped).
// R11: BARRIER-FREE GEMM. R5-R10 all had MfmaUtil<10%, VALUBusy<25% with
// barrier-coupled LDS staging (each __syncthreads drains vmcnt(0) -> exposes
// HBM latency every chunk). Here B-fragments are built directly from global x
// (lane m16=d, g=k-octet: 8 stride-3KB scalars; 16 lanes/k = full 64B segs),
// normalized+split in registers. No LDS, no __syncthreads in the GEMM.

#define B_   64
#define N_   196
#define D_   768
#define KQ   7     // 7 chunks of 32 k = 224 (padded)
#define OPAD 256

typedef __attribute__((ext_vector_type(8))) short bf16x8;
typedef __attribute__((ext_vector_type(4))) float f32x4;

__device__ __forceinline__ unsigned short bf16_rne(float f) {
    unsigned u = __builtin_bit_cast(unsigned, f);
    u += 0x7FFFu + ((u >> 16) & 1u);
    return (unsigned short)(u >> 16);
}
__device__ __forceinline__ float bf16_to_f(unsigned short h) {
    unsigned u = ((unsigned)h) << 16;
    return __builtin_bit_cast(float, u);
}

// Wfh/Wfl frag-packed: addr = (((o>>4)*KQ + (k>>5))*4 + ((k>>3)&3))*128
//                             + (o&15)*8 + (k&7)
__global__ void prep_w_kernel(const float* __restrict__ sw,
                              const float* __restrict__ sb,
                              const float* __restrict__ dw,
                              unsigned short* __restrict__ Wfh,
                              unsigned short* __restrict__ Wfl,
                              float* __restrict__ rowsum,
                              float* __restrict__ cvec) {
    int o = blockIdx.x;   // 0..255 (>=196 zero rows)
    int t = threadIdx.x;  // k index; only t<224 stored
    float w0 = 0.f, w1 = 0.f;
    if (o < N_) { w0 = dw[o * 2 + 0]; w1 = dw[o * 2 + 1]; }
    float val = 0.f, sbp = 0.f;
    if (o < N_ && t < N_) {
        val = w0 * sw[(o * 2 + 0) * N_ + t] + w1 * sw[(o * 2 + 1) * N_ + t];
        sbp = w0 * sb[(o * 2 + 0) * N_ + t] + w1 * sb[(o * 2 + 1) * N_ + t];
    }
    if (t < KQ * 32) {
        unsigned short h = bf16_rne(val);
        int addr = (((o >> 4) * KQ + (t >> 5)) * 4 + ((t >> 3) & 3)) * 128
                 + (o & 15) * 8 + (t & 7);
        Wfh[addr] = h;
        Wfl[addr] = bf16_rne(val - bf16_to_f(h));
    }
    __shared__ float r1[256], r2[256];
    r1[t] = val; r2[t] = sbp;
    __syncthreads();
    for (int s = 128; s > 0; s >>= 1) {
        if (t < s) { r1[t] += r1[t + s]; r2[t] += r2[t + s]; }
        __syncthreads();
    }
    if (t == 0) { rowsum[o] = r1[0]; cvec[o] = r2[0]; }
}

__global__ void ln_stats_kernel(const float* __restrict__ x,
                                float* __restrict__ mu,
                                float* __restrict__ rstd) {
    int wave = threadIdx.x >> 6;
    int lane = threadIdx.x & 63;
    int row  = blockIdx.x * 4 + wave;
    const float4* xr = reinterpret_cast<const float4*>(x + (size_t)row * D_);
    float4 v0 = xr[lane];
    float4 v1 = xr[lane + 64];
    float4 v2 = xr[lane + 128];
    float s = v0.x + v0.y + v0.z + v0.w
            + v1.x + v1.y + v1.z + v1.w
            + v2.x + v2.y + v2.z + v2.w;
    #pragma unroll
    for (int off = 32; off >= 1; off >>= 1) s += __shfl_xor(s, off);
    float m = s * (1.0f / D_);
    float q = 0.f;
    {
        float d;
        d = v0.x - m; q += d * d;  d = v0.y - m; q += d * d;
        d = v0.z - m; q += d * d;  d = v0.w - m; q += d * d;
        d = v1.x - m; q += d * d;  d = v1.y - m; q += d * d;
        d = v1.z - m; q += d * d;  d = v1.w - m; q += d * d;
        d = v2.x - m; q += d * d;  d = v2.y - m; q += d * d;
        d = v2.z - m; q += d * d;  d = v2.w - m; q += d * d;
    }
    #pragma unroll
    for (int off = 32; off >= 1; off >>= 1) q += __shfl_xor(q, off);
    if (lane == 0) {
        mu[row]   = m;
        rstd[row] = rsqrtf(q * (1.0f / D_) + 1e-5f);
    }
}

// Grid: (13 o-tiles x 3 d-groups, 64 b). Block: 256 thr = 4 waves.
// Wave w: o-rows [ot*16, ot*16+16), d = dg*256 + w*64 .. +64 (4 nf frags).
// No LDS, no barriers. Per chunk: A frag-pair from L2, per nf 8 direct
// global B scalars -> normalize -> hi/lo split -> 3 MFMA.
__global__ __launch_bounds__(256, 2) void gemm_mfma_kernel(
    const float* __restrict__ x,
    const float* __restrict__ ln_w,
    const float* __restrict__ ln_b,
    const unsigned short* __restrict__ Wfh,
    const unsigned short* __restrict__ Wfl,
    const float* __restrict__ rowsum,
    const float* __restrict__ cvec,
    const float* __restrict__ mu,
    const float* __restrict__ rstd,
    float* __restrict__ out) {
    const int b  = blockIdx.y;
    const int ot = blockIdx.x % 13;
    const int dg = blockIdx.x / 13;
    const int t = threadIdx.x;
    const int w = t >> 6, lane = t & 63;
    const int m16 = lane & 15, g = lane >> 4;
    const int d0 = dg * 256 + w * 64;

    const float* xb  = x + (size_t)b * (N_ * D_);
    const float* mub = mu + b * N_;
    const float* rsb = rstd + b * N_;

    f32x4 acc[4];
    #pragma unroll
    for (int j = 0; j < 4; ++j) acc[j] = (f32x4){0.f, 0.f, 0.f, 0.f};

    #pragma unroll
    for (int c = 0; c < KQ; ++c) {
        // ---- per-chunk k-slice stats: a[e]=rstd, off[e]=-mu*rstd ----
        float a_[8], off_[8];
        if (c < 6 || g == 0) {
            const int kb = c * 32 + g * 8;
            float4 m0 = *reinterpret_cast<const float4*>(mub + kb);
            float4 m1 = *reinterpret_cast<const float4*>(mub + kb + 4);
            float4 r0 = *reinterpret_cast<const float4*>(rsb + kb);
            float4 r1 = *reinterpret_cast<const float4*>(rsb + kb + 4);
            a_[0]=r0.x; a_[1]=r0.y; a_[2]=r0.z; a_[3]=r0.w;
            a_[4]=r1.x; a_[5]=r1.y; a_[6]=r1.z; a_[7]=r1.w;
            off_[0]=-m0.x*r0.x; off_[1]=-m0.y*r0.y; off_[2]=-m0.z*r0.z; off_[3]=-m0.w*r0.w;
            off_[4]=-m1.x*r1.x; off_[5]=-m1.y*r1.y; off_[6]=-m1.z*r1.z; off_[7]=-m1.w*r1.w;
        } else {
            #pragma unroll
            for (int e = 0; e < 8; ++e) { a_[e] = 0.f; off_[e] = 0.f; }
        }
        // ---- A fragments (frag-packed, L2-resident) ----
        const size_t ab = ((size_t)(ot * KQ + c) * 4 + g) * 128 + m16 * 8;
        bf16x8 ah = *reinterpret_cast<const bf16x8*>(Wfh + ab);
        bf16x8 al = *reinterpret_cast<const bf16x8*>(Wfl + ab);
        // ---- per-nf: direct-global B frags ----
        #pragma unroll
        for (int nf = 0; nf < 4; ++nf) {
            const int d = d0 + nf * 16 + m16;
            const float* xp = xb + (size_t)(c * 32 + g * 8) * D_ + d;
            float xv[8];
            #pragma unroll
            for (int e = 0; e < 8; ++e) {
                bool kv = (c < 6) || (g == 0 && e < 4);
                xv[e] = kv ? xp[(size_t)e * D_] : 0.f;
            }
            bf16x8 bh, bl;
            #pragma unroll
            for (int e = 0; e < 8; ++e) {
                float v = fmaf(xv[e], a_[e], (c < 6 || (g == 0 && e < 4)) ? off_[e] : 0.f);
                unsigned short h = bf16_rne(v);
                bh[e] = (short)h;
                bl[e] = (short)bf16_rne(v - bf16_to_f(h));
            }
            acc[nf] = __builtin_amdgcn_mfma_f32_16x16x32_bf16(ah, bh, acc[nf], 0, 0, 0);
            acc[nf] = __builtin_amdgcn_mfma_f32_16x16x32_bf16(ah, bl, acc[nf], 0, 0, 0);
            acc[nf] = __builtin_amdgcn_mfma_f32_16x16x32_bf16(al, bh, acc[nf], 0, 0, 0);
        }
    }

    // ---- epilogue: T = lnw*acc + lnb*rowsum + c; out = x*(gelu(T)+1) ----
    // C/D layout: col(d) = lane&15 (=m16), row(o) = (lane>>4)*4 + reg
    float lwv[4], lbv[4];
    #pragma unroll
    for (int nf = 0; nf < 4; ++nf) {
        lwv[nf] = ln_w[d0 + nf * 16 + m16];
        lbv[nf] = ln_b[d0 + nf * 16 + m16];
    }
    #pragma unroll
    for (int r = 0; r < 4; ++r) {
        const int o = ot * 16 + g * 4 + r;
        if (o < N_) {
            const float rs = rowsum[o], cc = cvec[o];
            #pragma unroll
            for (int nf = 0; nf < 4; ++nf) {
                const int d = d0 + nf * 16 + m16;
                float T = fmaf(lwv[nf], acc[nf][r], fmaf(lbv[nf], rs, cc));
                float gl = 0.5f * T * (1.0f + erff(T * 0.70710678118654752f));
                out[((size_t)(b * N_ + o)) * D_ + d] = xb[(size_t)o * D_ + d] * (gl + 1.0f);
            }
        }
    }
}

extern "C" void kernel_launch(void* const* d_in, const int* in_sizes, int n_in,
                              void* d_out, int out_size, void* d_ws, size_t ws_size,
                              hipStream_t stream) {
    const float* x    = (const float*)d_in[0];
    const float* ln_w = (const float*)d_in[1];
    const float* ln_b = (const float*)d_in[2];
    const float* sw   = (const float*)d_in[3];
    const float* sb   = (const float*)d_in[4];
    const float* dw   = (const float*)d_in[5];
    float* out = (float*)d_out;

    float* wsf = (float*)d_ws;
    float* mu     = wsf;                       // 12544 + 64 pad
    float* rstd   = mu + 12608;                // 12544 + 64 pad
    float* rowsum = rstd + 12608;              // 256
    float* cvec   = rowsum + OPAD;             // 256
    unsigned short* Wfh = (unsigned short*)(cvec + OPAD);  // 16*7*512 u16
    unsigned short* Wfl = Wfh + (OPAD / 16) * KQ * 512;

    prep_w_kernel<<<OPAD, 256, 0, stream>>>(sw, sb, dw, Wfh, Wfl, rowsum, cvec);
    ln_stats_kernel<<<(B_ * N_) / 4, 256, 0, stream>>>(x, mu, rstd);
    gemm_mfma_kernel<<<dim3(39, B_), 256, 0, stream>>>(
        x, ln_w, ln_b, Wfh, Wfl, rowsum, cvec, mu, rstd, out);
}

// Round 12
// 59.500 us; speedup vs baseline: 1.4416x; 1.4416x over previous
//
#include <hip/hip_runtime.h>
#include <math.h>

// Shapes: x:(64,196,768) f32, ln_w/ln_b:(768,), sw/sb:(196,2,196), dw:(196,2)
//   W[o,n] = sum_m dw[o,m]*sw[o,m,n];  c[o] = sum_m dw[o,m]*sum_n sb[o,m,n]
//   t[b,o,d] = ln_w[d]*sum_n W[o,n]*xh[b,n,d] + ln_b[d]*rowsum[o] + c[o]
//   out[b,o,d] = x[b,o,d] * (gelu_erf(t) + 1)
// bf16 split MFMA: acc += Whi*Bhi + Whi*Blo + Wlo*Bhi (lo*lo dropped).
// R12: barrier-free (R11's high-utilization property) + full-o blocks
// (R10's exact-traffic property). Grid (12 dt, 64 b), 8 waves cover all
// 256 o; B-frags built from global f32 x in-register (no LDS, no syncs);
// 8-wave B reuse is L1-served (per-chunk footprint ~12KB << 32KB L1).

#define B_   64
#define N_   196
#define D_   768
#define KQ   7     // 7 chunks of 32 k = 224 (padded)
#define OPAD 256

typedef __attribute__((ext_vector_type(8))) short bf16x8;
typedef __attribute__((ext_vector_type(4))) float f32x4;

__device__ __forceinline__ unsigned short bf16_rne(float f) {
    unsigned u = __builtin_bit_cast(unsigned, f);
    u += 0x7FFFu + ((u >> 16) & 1u);
    return (unsigned short)(u >> 16);
}
__device__ __forceinline__ float bf16_to_f(unsigned short h) {
    unsigned u = ((unsigned)h) << 16;
    return __builtin_bit_cast(float, u);
}

// Wfh/Wfl frag-packed: addr = (((o>>4)*KQ + (k>>5))*4 + ((k>>3)&3))*128
//                             + (o&15)*8 + (k&7);  o>=196 rows are zero.
__global__ void prep_w_kernel(const float* __restrict__ sw,
                              const float* __restrict__ sb,
                              const float* __restrict__ dw,
                              unsigned short* __restrict__ Wfh,
                              unsigned short* __restrict__ Wfl,
                              float* __restrict__ rowsum,
                              float* __restrict__ cvec) {
    int o = blockIdx.x;   // 0..255
    int t = threadIdx.x;  // k; only t<224 stored
    float w0 = 0.f, w1 = 0.f;
    if (o < N_) { w0 = dw[o * 2 + 0]; w1 = dw[o * 2 + 1]; }
    float val = 0.f, sbp = 0.f;
    if (o < N_ && t < N_) {
        val = w0 * sw[(o * 2 + 0) * N_ + t] + w1 * sw[(o * 2 + 1) * N_ + t];
        sbp = w0 * sb[(o * 2 + 0) * N_ + t] + w1 * sb[(o * 2 + 1) * N_ + t];
    }
    if (t < KQ * 32) {
        unsigned short h = bf16_rne(val);
        int addr = (((o >> 4) * KQ + (t >> 5)) * 4 + ((t >> 3) & 3)) * 128
                 + (o & 15) * 8 + (t & 7);
        Wfh[addr] = h;
        Wfl[addr] = bf16_rne(val - bf16_to_f(h));
    }
    __shared__ float r1[256], r2[256];
    r1[t] = val; r2[t] = sbp;
    __syncthreads();
    for (int s = 128; s > 0; s >>= 1) {
        if (t < s) { r1[t] += r1[t + s]; r2[t] += r2[t + s]; }
        __syncthreads();
    }
    if (t == 0) { rowsum[o] = r1[0]; cvec[o] = r2[0]; }
}

__global__ void ln_stats_kernel(const float* __restrict__ x,
                                float* __restrict__ mu,
                                float* __restrict__ rstd) {
    int wave = threadIdx.x >> 6;
    int lane = threadIdx.x & 63;
    int row  = blockIdx.x * 4 + wave;
    const float4* xr = reinterpret_cast<const float4*>(x + (size_t)row * D_);
    float4 v0 = xr[lane];
    float4 v1 = xr[lane + 64];
    float4 v2 = xr[lane + 128];
    float s = v0.x + v0.y + v0.z + v0.w
            + v1.x + v1.y + v1.z + v1.w
            + v2.x + v2.y + v2.z + v2.w;
    #pragma unroll
    for (int off = 32; off >= 1; off >>= 1) s += __shfl_xor(s, off);
    float m = s * (1.0f / D_);
    float q = 0.f;
    {
        float d;
        d = v0.x - m; q += d * d;  d = v0.y - m; q += d * d;
        d = v0.z - m; q += d * d;  d = v0.w - m; q += d * d;
        d = v1.x - m; q += d * d;  d = v1.y - m; q += d * d;
        d = v1.z - m; q += d * d;  d = v1.w - m; q += d * d;
        d = v2.x - m; q += d * d;  d = v2.y - m; q += d * d;
        d = v2.z - m; q += d * d;  d = v2.w - m; q += d * d;
    }
    #pragma unroll
    for (int off = 32; off >= 1; off >>= 1) q += __shfl_xor(q, off);
    if (lane == 0) {
        mu[row]   = m;
        rstd[row] = rsqrtf(q * (1.0f / D_) + 1e-5f);
    }
}

// Grid (12 d-tiles, 64 b), 512 threads = 8 waves, NO LDS, NO barriers.
// Wave w: o-frags f = w*2+{0,1} (o rows f*16..f*16+16), d tile d0..d0+64.
// Per chunk c: 32 B-scalars (k=c*32+g*8+e, d=d0+nf*16+m16; 16 lanes/k share
// a 64B segment, 8-wave reuse L1-served) -> normalize -> hi/lo split;
// A frag-pairs from L2 (frag-packed); 24 MFMA.
__global__ __launch_bounds__(512, 4) void gemm_mfma_kernel(
    const float* __restrict__ x,
    const float* __restrict__ ln_w,
    const float* __restrict__ ln_b,
    const unsigned short* __restrict__ Wfh,
    const unsigned short* __restrict__ Wfl,
    const float* __restrict__ rowsum,
    const float* __restrict__ cvec,
    const float* __restrict__ mu,
    const float* __restrict__ rstd,
    float* __restrict__ out) {
    const int b  = blockIdx.y;
    const int d0 = blockIdx.x * 64;
    const int t = threadIdx.x;
    const int w = t >> 6, lane = t & 63;
    const int m16 = lane & 15, g = lane >> 4;

    const float* xb  = x + (size_t)b * (N_ * D_);
    const float* mub = mu + b * N_;
    const float* rsb = rstd + b * N_;

    f32x4 acc[2][4];
    #pragma unroll
    for (int i = 0; i < 2; ++i)
        #pragma unroll
        for (int j = 0; j < 4; ++j)
            acc[i][j] = (f32x4){0.f, 0.f, 0.f, 0.f};

    #pragma unroll
    for (int c = 0; c < KQ; ++c) {
        const int kb = c * 32 + g * 8;
        // ---- B scalars first (longest latency; predicated for fault safety)
        const float* xp = xb + (size_t)kb * D_ + d0 + m16;
        float xv[4][8];
        #pragma unroll
        for (int nf = 0; nf < 4; ++nf)
            #pragma unroll
            for (int e = 0; e < 8; ++e)
                xv[nf][e] = (kb + e < N_) ? xp[(size_t)e * D_ + nf * 16] : 0.f;
        // ---- stats (L2; reads beyond row 196 hit padded/next-b data, but
        //      those k's have A == 0 so any finite value is harmless)
        float4 m0 = *reinterpret_cast<const float4*>(mub + kb);
        float4 m1 = *reinterpret_cast<const float4*>(mub + kb + 4);
        float4 r0 = *reinterpret_cast<const float4*>(rsb + kb);
        float4 r1 = *reinterpret_cast<const float4*>(rsb + kb + 4);
        float a_[8]   = {r0.x, r0.y, r0.z, r0.w, r1.x, r1.y, r1.z, r1.w};
        float off_[8] = {-m0.x * r0.x, -m0.y * r0.y, -m0.z * r0.z, -m0.w * r0.w,
                         -m1.x * r1.x, -m1.y * r1.y, -m1.z * r1.z, -m1.w * r1.w};
        // ---- A fragments (frag-packed, L2-resident)
        bf16x8 ah[2], al[2];
        #pragma unroll
        for (int mf = 0; mf < 2; ++mf) {
            const size_t ab = ((size_t)((w * 2 + mf) * KQ + c)) * 512 + lane * 8;
            ah[mf] = *reinterpret_cast<const bf16x8*>(Wfh + ab);
            al[mf] = *reinterpret_cast<const bf16x8*>(Wfl + ab);
        }
        // ---- split + MFMA
        #pragma unroll
        for (int nf = 0; nf < 4; ++nf) {
            bf16x8 bh, bl;
            #pragma unroll
            for (int e = 0; e < 8; ++e) {
                float v = fmaf(xv[nf][e], a_[e], off_[e]);
                unsigned short h = bf16_rne(v);
                bh[e] = (short)h;
                bl[e] = (short)bf16_rne(v - bf16_to_f(h));
            }
            #pragma unroll
            for (int mf = 0; mf < 2; ++mf) {
                acc[mf][nf] = __builtin_amdgcn_mfma_f32_16x16x32_bf16(ah[mf], bh, acc[mf][nf], 0, 0, 0);
                acc[mf][nf] = __builtin_amdgcn_mfma_f32_16x16x32_bf16(ah[mf], bl, acc[mf][nf], 0, 0, 0);
                acc[mf][nf] = __builtin_amdgcn_mfma_f32_16x16x32_bf16(al[mf], bh, acc[mf][nf], 0, 0, 0);
            }
        }
    }

    // ---- epilogue: T = lnw*acc + lnb*rowsum + c; out = x*(gelu(T)+1) ----
    // C/D layout: col(d) = lane&15, row(o within frag) = g*4 + r
    float lwv[4], lbv[4];
    #pragma unroll
    for (int nf = 0; nf < 4; ++nf) {
        lwv[nf] = ln_w[d0 + nf * 16 + m16];
        lbv[nf] = ln_b[d0 + nf * 16 + m16];
    }
    #pragma unroll
    for (int mf = 0; mf < 2; ++mf) {
        const int obase = (w * 2 + mf) * 16 + g * 4;
        f32x4 rs4 = *reinterpret_cast<const f32x4*>(rowsum + obase);
        f32x4 cc4 = *reinterpret_cast<const f32x4*>(cvec + obase);
        // prefetch x residual for this frag (predicated)
        float xres[4][4];
        #pragma unroll
        for (int r = 0; r < 4; ++r) {
            const int o = obase + r;
            #pragma unroll
            for (int nf = 0; nf < 4; ++nf)
                xres[r][nf] = (o < N_) ? xb[(size_t)o * D_ + d0 + nf * 16 + m16] : 0.f;
        }
        #pragma unroll
        for (int r = 0; r < 4; ++r) {
            const int o = obase + r;
            if (o < N_) {
                #pragma unroll
                for (int nf = 0; nf < 4; ++nf) {
                    const int d = d0 + nf * 16 + m16;
                    float T = fmaf(lwv[nf], acc[mf][nf][r], fmaf(lbv[nf], rs4[r], cc4[r]));
                    float gl = 0.5f * T * (1.0f + erff(T * 0.70710678118654752f));
                    out[((size_t)(b * N_ + o)) * D_ + d] = xres[r][nf] * (gl + 1.0f);
                }
            }
        }
    }
}

extern "C" void kernel_launch(void* const* d_in, const int* in_sizes, int n_in,
                              void* d_out, int out_size, void* d_ws, size_t ws_size,
                              hipStream_t stream) {
    const float* x    = (const float*)d_in[0];
    const float* ln_w = (const float*)d_in[1];
    const float* ln_b = (const float*)d_in[2];
    const float* sw   = (const float*)d_in[3];
    const float* sb   = (const float*)d_in[4];
    const float* dw   = (const float*)d_in[5];
    float* out = (float*)d_out;

    float* wsf = (float*)d_ws;
    float* mu     = wsf;                       // 12608 (12544 + pad)
    float* rstd   = mu + 12608;                // 12608
    float* rowsum = rstd + 12608;              // 256
    float* cvec   = rowsum + OPAD;             // 256
    unsigned short* Wfh = (unsigned short*)(cvec + OPAD);  // 16*7*512 u16
    unsigned short* Wfl = Wfh + 16 * KQ * 512;

    prep_w_kernel<<<OPAD, 256, 0, stream>>>(sw, sb, dw, Wfh, Wfl, rowsum, cvec);
    ln_stats_kernel<<<(B_ * N_) / 4, 256, 0, stream>>>(x, mu, rstd);
    gemm_mfma_kernel<<<dim3(12, B_), 512, 0, stream>>>(
        x, ln_w, ln_b, Wfh, Wfl, rowsum, cvec, mu, rstd, out);
}

// Round 13
// 55.344 us; speedup vs baseline: 1.5499x; 1.0751x over previous
//
#include <hip/hip_runtime.h>
#include <math.h>

// Shapes: x:(64,196,768) f32, ln_w/ln_b:(768,), sw/sb:(196,2,196), dw:(196,2)
//   W[o,n] = sum_m dw[o,m]*sw[o,m,n];  c[o] = sum_m dw[o,m]*sum_n sb[o,m,n]
//   t[b,o,d] = sum_n W[o,n]*(xh*ln_w)[b,n,d] + ln_b[d]*rowsum[o] + c[o]
//   out[b,o,d] = x[b,o,d] * (gelu_erf(t) + 1)
// bf16 split MFMA: acc += Whi*Bhi + Whi*Blo + Wlo*Bhi (lo*lo dropped).
// R13: producer/consumer. R12 was VMEM-latency-bound (224 scalar 4B loads at
// 3KB stride, L3-served). Producer kernel fuses LN stats + normalize + ln_w
// fold + hi/lo split and writes B pre-packed in fragment order [b][koct][d][k8]
// (LDS transpose, coalesced). Consumer GEMM reads contiguous b128 streams,
// no LDS, no barriers. Falls back to R10 path if ws_size < 44.3 MB.

#define B_   64
#define N_   196
#define D_   768
#define KQ   7     // 7 chunks of 32 k
#define NKO  28    // 28 k-octets = 224 padded k
#define OPAD 256

typedef __attribute__((ext_vector_type(8))) short bf16x8;
typedef __attribute__((ext_vector_type(4))) float f32x4;

__device__ __forceinline__ unsigned short bf16_rne(float f) {
    unsigned u = __builtin_bit_cast(unsigned, f);
    u += 0x7FFFu + ((u >> 16) & 1u);
    return (unsigned short)(u >> 16);
}
__device__ __forceinline__ float bf16_to_f(unsigned short h) {
    unsigned u = ((unsigned)h) << 16;
    return __builtin_bit_cast(float, u);
}

// Wfh/Wfl frag-packed: addr = (((o>>4)*KQ + (k>>5))*4 + ((k>>3)&3))*128
//                             + (o&15)*8 + (k&7);  o>=196 / k>=224 zeroed.
__global__ void prep_w_kernel(const float* __restrict__ sw,
                              const float* __restrict__ sb,
                              const float* __restrict__ dw,
                              unsigned short* __restrict__ Wfh,
                              unsigned short* __restrict__ Wfl,
                              float* __restrict__ rowsum,
                              float* __restrict__ cvec) {
    int o = blockIdx.x;   // 0..255
    int t = threadIdx.x;  // k; only t<224 stored
    float w0 = 0.f, w1 = 0.f;
    if (o < N_) { w0 = dw[o * 2 + 0]; w1 = dw[o * 2 + 1]; }
    float val = 0.f, sbp = 0.f;
    if (o < N_ && t < N_) {
        val = w0 * sw[(o * 2 + 0) * N_ + t] + w1 * sw[(o * 2 + 1) * N_ + t];
        sbp = w0 * sb[(o * 2 + 0) * N_ + t] + w1 * sb[(o * 2 + 1) * N_ + t];
    }
    if (t < KQ * 32) {
        unsigned short h = bf16_rne(val);
        int addr = (((o >> 4) * KQ + (t >> 5)) * 4 + ((t >> 3) & 3)) * 128
                 + (o & 15) * 8 + (t & 7);
        Wfh[addr] = h;
        Wfl[addr] = bf16_rne(val - bf16_to_f(h));
    }
    __shared__ float r1[256], r2[256];
    r1[t] = val; r2[t] = sbp;
    __syncthreads();
    for (int s = 128; s > 0; s >>= 1) {
        if (t < s) { r1[t] += r1[t + s]; r2[t] += r2[t + s]; }
        __syncthreads();
    }
    if (t == 0) { rowsum[o] = r1[0]; cvec[o] = r2[0]; }
}

// ---------------- PRIMARY PATH ----------------
// Producer: block (koct, b), 512 thr = 8 waves; wave w owns row k=koct*8+w.
// One-pass stats (E[x^2]-mu^2), normalize*ln_w to LDS f32 [8][768], then
// transpose: thread d reads column of 8, splits hi/lo, writes Bh/Bl at
// [((b*28+koct)*768+d)*8] -- 16B/thread contiguous stores.
__global__ __launch_bounds__(512) void ln_split_kernel(
    const float* __restrict__ x,
    const float* __restrict__ ln_w,
    unsigned short* __restrict__ Bh,
    unsigned short* __restrict__ Bl) {
    const int koct = blockIdx.x, b = blockIdx.y;
    const int t = threadIdx.x, w = t >> 6, lane = t & 63;
    const int k = koct * 8 + w;
    __shared__ float xs[8][768];

    float4 v0 = make_float4(0.f, 0.f, 0.f, 0.f);
    float4 v1 = v0, v2 = v0;
    if (k < N_) {
        const float4* xr = reinterpret_cast<const float4*>(x + ((size_t)b * N_ + k) * D_);
        v0 = xr[lane]; v1 = xr[lane + 64]; v2 = xr[lane + 128];
    }
    float s = v0.x + v0.y + v0.z + v0.w
            + v1.x + v1.y + v1.z + v1.w
            + v2.x + v2.y + v2.z + v2.w;
    float q = v0.x*v0.x + v0.y*v0.y + v0.z*v0.z + v0.w*v0.w
            + v1.x*v1.x + v1.y*v1.y + v1.z*v1.z + v1.w*v1.w
            + v2.x*v2.x + v2.y*v2.y + v2.z*v2.z + v2.w*v2.w;
    #pragma unroll
    for (int off = 32; off >= 1; off >>= 1) {
        s += __shfl_xor(s, off);
        q += __shfl_xor(q, off);
    }
    const float mu   = s * (1.0f / D_);
    const float var  = q * (1.0f / D_) - mu * mu;
    const float rstd = rsqrtf(var + 1e-5f);

    const float4* lw4 = reinterpret_cast<const float4*>(ln_w);
    float4 w0 = lw4[lane], w1 = lw4[lane + 64], w2 = lw4[lane + 128];
    float4 o0, o1, o2;
    o0.x = (v0.x - mu) * rstd * w0.x;  o0.y = (v0.y - mu) * rstd * w0.y;
    o0.z = (v0.z - mu) * rstd * w0.z;  o0.w = (v0.w - mu) * rstd * w0.w;
    o1.x = (v1.x - mu) * rstd * w1.x;  o1.y = (v1.y - mu) * rstd * w1.y;
    o1.z = (v1.z - mu) * rstd * w1.z;  o1.w = (v1.w - mu) * rstd * w1.w;
    o2.x = (v2.x - mu) * rstd * w2.x;  o2.y = (v2.y - mu) * rstd * w2.y;
    o2.z = (v2.z - mu) * rstd * w2.z;  o2.w = (v2.w - mu) * rstd * w2.w;
    *reinterpret_cast<float4*>(&xs[w][lane * 4])       = o0;
    *reinterpret_cast<float4*>(&xs[w][lane * 4 + 256]) = o1;
    *reinterpret_cast<float4*>(&xs[w][lane * 4 + 512]) = o2;
    __syncthreads();

    for (int d = t; d < D_; d += 512) {
        bf16x8 hv, lv;
        #pragma unroll
        for (int kk = 0; kk < 8; ++kk) {
            float v = xs[kk][d];
            unsigned short h = bf16_rne(v);
            hv[kk] = (short)h;
            lv[kk] = (short)bf16_rne(v - bf16_to_f(h));
        }
        const size_t base = (((size_t)b * NKO + koct) * D_ + d) * 8;
        *reinterpret_cast<bf16x8*>(Bh + base) = hv;
        *reinterpret_cast<bf16x8*>(Bl + base) = lv;
    }
}

// Consumer GEMM: grid (12 dt, 64 b), 512 thr = 8 waves, NO LDS, NO barriers.
// Wave w: o-frags w*2+{0,1}; per chunk 8 contiguous b128 B-loads + 4 A-loads
// + 24 MFMA. ln_w already folded into B by the producer.
__global__ __launch_bounds__(512, 4) void gemm_bpk_kernel(
    const float* __restrict__ x,
    const float* __restrict__ ln_b,
    const unsigned short* __restrict__ Wfh,
    const unsigned short* __restrict__ Wfl,
    const unsigned short* __restrict__ Bh,
    const unsigned short* __restrict__ Bl,
    const float* __restrict__ rowsum,
    const float* __restrict__ cvec,
    float* __restrict__ out) {
    const int b  = blockIdx.y;
    const int d0 = blockIdx.x * 64;
    const int t = threadIdx.x;
    const int w = t >> 6, lane = t & 63;
    const int m16 = lane & 15, g = lane >> 4;

    const float* xb = x + (size_t)b * (N_ * D_);

    f32x4 acc[2][4];
    #pragma unroll
    for (int i = 0; i < 2; ++i)
        #pragma unroll
        for (int j = 0; j < 4; ++j)
            acc[i][j] = (f32x4){0.f, 0.f, 0.f, 0.f};

    #pragma unroll
    for (int c = 0; c < KQ; ++c) {
        bf16x8 ah[2], al[2], bh[4], bl[4];
        const size_t krow = ((size_t)b * NKO + c * 4 + g) * D_;
        #pragma unroll
        for (int nf = 0; nf < 4; ++nf) {
            const size_t e = (krow + d0 + nf * 16 + m16) * 8;
            bh[nf] = *reinterpret_cast<const bf16x8*>(Bh + e);
            bl[nf] = *reinterpret_cast<const bf16x8*>(Bl + e);
        }
        #pragma unroll
        for (int mf = 0; mf < 2; ++mf) {
            const size_t ab = ((size_t)((w * 2 + mf) * KQ + c)) * 512 + lane * 8;
            ah[mf] = *reinterpret_cast<const bf16x8*>(Wfh + ab);
            al[mf] = *reinterpret_cast<const bf16x8*>(Wfl + ab);
        }
        #pragma unroll
        for (int nf = 0; nf < 4; ++nf) {
            #pragma unroll
            for (int mf = 0; mf < 2; ++mf) {
                acc[mf][nf] = __builtin_amdgcn_mfma_f32_16x16x32_bf16(ah[mf], bh[nf], acc[mf][nf], 0, 0, 0);
                acc[mf][nf] = __builtin_amdgcn_mfma_f32_16x16x32_bf16(ah[mf], bl[nf], acc[mf][nf], 0, 0, 0);
                acc[mf][nf] = __builtin_amdgcn_mfma_f32_16x16x32_bf16(al[mf], bh[nf], acc[mf][nf], 0, 0, 0);
            }
        }
    }

    // epilogue: T = acc + lnb[d]*rowsum[o] + c[o]; out = x*(gelu(T)+1)
    // C/D layout: col(d) = lane&15, row(o within frag) = g*4 + r
    float lbv[4];
    #pragma unroll
    for (int nf = 0; nf < 4; ++nf) lbv[nf] = ln_b[d0 + nf * 16 + m16];
    #pragma unroll
    for (int mf = 0; mf < 2; ++mf) {
        const int obase = (w * 2 + mf) * 16 + g * 4;
        f32x4 rs4 = *reinterpret_cast<const f32x4*>(rowsum + obase);
        f32x4 cc4 = *reinterpret_cast<const f32x4*>(cvec + obase);
        float xres[4][4];
        #pragma unroll
        for (int r = 0; r < 4; ++r) {
            const int o = obase + r;
            #pragma unroll
            for (int nf = 0; nf < 4; ++nf)
                xres[r][nf] = (o < N_) ? xb[(size_t)o * D_ + d0 + nf * 16 + m16] : 0.f;
        }
        #pragma unroll
        for (int r = 0; r < 4; ++r) {
            const int o = obase + r;
            if (o < N_) {
                #pragma unroll
                for (int nf = 0; nf < 4; ++nf) {
                    const int d = d0 + nf * 16 + m16;
                    float T = acc[mf][nf][r] + fmaf(lbv[nf], rs4[r], cc4[r]);
                    float gl = 0.5f * T * (1.0f + erff(T * 0.70710678118654752f));
                    out[((size_t)(b * N_ + o)) * D_ + d] = xres[r][nf] * (gl + 1.0f);
                }
            }
        }
    }
}

// ---------------- FALLBACK PATH (R10, proven) ----------------
__global__ void ln_stats_kernel(const float* __restrict__ x,
                                float* __restrict__ mu,
                                float* __restrict__ rstd) {
    int wave = threadIdx.x >> 6;
    int lane = threadIdx.x & 63;
    int row  = blockIdx.x * 4 + wave;
    const float4* xr = reinterpret_cast<const float4*>(x + (size_t)row * D_);
    float4 v0 = xr[lane];
    float4 v1 = xr[lane + 64];
    float4 v2 = xr[lane + 128];
    float s = v0.x + v0.y + v0.z + v0.w
            + v1.x + v1.y + v1.z + v1.w
            + v2.x + v2.y + v2.z + v2.w;
    #pragma unroll
    for (int off = 32; off >= 1; off >>= 1) s += __shfl_xor(s, off);
    float m = s * (1.0f / D_);
    float q = 0.f;
    {
        float d;
        d = v0.x - m; q += d * d;  d = v0.y - m; q += d * d;
        d = v0.z - m; q += d * d;  d = v0.w - m; q += d * d;
        d = v1.x - m; q += d * d;  d = v1.y - m; q += d * d;
        d = v1.z - m; q += d * d;  d = v1.w - m; q += d * d;
        d = v2.x - m; q += d * d;  d = v2.y - m; q += d * d;
        d = v2.z - m; q += d * d;  d = v2.w - m; q += d * d;
    }
    #pragma unroll
    for (int off = 32; off >= 1; off >>= 1) q += __shfl_xor(q, off);
    if (lane == 0) {
        mu[row]   = m;
        rstd[row] = rsqrtf(q * (1.0f / D_) + 1e-5f);
    }
}

#define LOADC(s, c) do {                                                      \
    _Pragma("unroll")                                                         \
    for (int e = 0; e < 4; ++e) {                                             \
        const int k = (c) * 32 + w * 4 + e;                                   \
        if (k < N_) {                                                         \
            xv[s][e]  = xb[(size_t)k * D_ + d0 + lane];                       \
            mus[s][e] = mub[k];                                               \
            rss[s][e] = rsb[k];                                               \
        } else { xv[s][e] = 0.f; mus[s][e] = 0.f; rss[s][e] = 0.f; }          \
    } } while (0)

#define WRITEC(s) do {                                                        \
    short4 hv, lv; short* hp = &hv.x; short* lp = &lv.x;                      \
    _Pragma("unroll")                                                         \
    for (int e = 0; e < 4; ++e) {                                             \
        float v = (xv[s][e] - mus[s][e]) * rss[s][e];                         \
        unsigned short h = bf16_rne(v);                                       \
        hp[e] = (short)h;                                                     \
        lp[e] = (short)bf16_rne(v - bf16_to_f(h));                            \
    }                                                                         \
    const int ea = ((w >> 1) * 64 + lane) * 8 + (w & 1) * 4;                  \
    *reinterpret_cast<short4*>(&BsH[s][ea]) = hv;                             \
    *reinterpret_cast<short4*>(&BsL[s][ea]) = lv; } while (0)

#define LOADA(slot, c) do {                                                   \
    _Pragma("unroll")                                                         \
    for (int mf = 0; mf < 2; ++mf) {                                          \
        const size_t ab = ((size_t)((w * 2 + mf) * KQ + (c)) * 512) + lane * 8;\
        ah[slot][mf] = *reinterpret_cast<const bf16x8*>(Wfh + ab);            \
        al[slot][mf] = *reinterpret_cast<const bf16x8*>(Wfl + ab);            \
    } } while (0)

__global__ __launch_bounds__(512, 4) void gemm_lds_kernel(
    const float* __restrict__ x,
    const float* __restrict__ ln_w,
    const float* __restrict__ ln_b,
    const unsigned short* __restrict__ Wfh,
    const unsigned short* __restrict__ Wfl,
    const float* __restrict__ rowsum,
    const float* __restrict__ cvec,
    const float* __restrict__ mu,
    const float* __restrict__ rstd,
    float* __restrict__ out) {
    const int b  = blockIdx.y;
    const int d0 = blockIdx.x * 64;
    const int t = threadIdx.x;
    const int w = t >> 6, lane = t & 63;
    const int m16 = lane & 15, g = lane >> 4;

    __shared__ __align__(16) unsigned short BsH[2][2048];
    __shared__ __align__(16) unsigned short BsL[2][2048];

    const float* xb  = x + (size_t)b * (N_ * D_);
    const float* mub = mu + b * N_;
    const float* rsb = rstd + b * N_;

    float xv[2][4], mus[2][4], rss[2][4];
    bf16x8 ah[2][2], al[2][2];

    f32x4 acc[2][4];
    #pragma unroll
    for (int i = 0; i < 2; ++i)
        #pragma unroll
        for (int j = 0; j < 4; ++j)
            acc[i][j] = (f32x4){0.f, 0.f, 0.f, 0.f};

    LOADC(0, 0);
    LOADC(1, 1);
    LOADA(0, 0);
    WRITEC(0);
    __syncthreads();

    #pragma unroll
    for (int c = 0; c < KQ; ++c) {
        const int s = c & 1;
        if (c > 0) {
            WRITEC(s);
            __syncthreads();
        }
        if (c + 2 < KQ) LOADC(s, c + 2);
        if (c + 1 < KQ) LOADA((c + 1) & 1, c + 1);
        #pragma unroll
        for (int nf = 0; nf < 4; ++nf) {
            const int ba = (g * 64 + nf * 16 + m16) * 8;
            bf16x8 bh = *reinterpret_cast<const bf16x8*>(&BsH[s][ba]);
            bf16x8 bl = *reinterpret_cast<const bf16x8*>(&BsL[s][ba]);
            #pragma unroll
            for (int mf = 0; mf < 2; ++mf) {
                acc[mf][nf] = __builtin_amdgcn_mfma_f32_16x16x32_bf16(ah[s][mf], bh, acc[mf][nf], 0, 0, 0);
                acc[mf][nf] = __builtin_amdgcn_mfma_f32_16x16x32_bf16(ah[s][mf], bl, acc[mf][nf], 0, 0, 0);
                acc[mf][nf] = __builtin_amdgcn_mfma_f32_16x16x32_bf16(al[s][mf], bh, acc[mf][nf], 0, 0, 0);
            }
        }
    }

    float lwv[4], lbv[4];
    #pragma unroll
    for (int nf = 0; nf < 4; ++nf) {
        lwv[nf] = ln_w[d0 + nf * 16 + m16];
        lbv[nf] = ln_b[d0 + nf * 16 + m16];
    }
    #pragma unroll
    for (int mf = 0; mf < 2; ++mf) {
        #pragma unroll
        for (int r = 0; r < 4; ++r) {
            const int o = w * 32 + mf * 16 + g * 4 + r;
            if (o < N_) {
                const float rs = rowsum[o], cc = cvec[o];
                #pragma unroll
                for (int nf = 0; nf < 4; ++nf) {
                    const int d = d0 + nf * 16 + m16;
                    float T = fmaf(lwv[nf], acc[mf][nf][r], fmaf(lbv[nf], rs, cc));
                    float gl = 0.5f * T * (1.0f + erff(T * 0.70710678118654752f));
                    out[((size_t)(b * N_ + o)) * D_ + d] = xb[(size_t)o * D_ + d] * (gl + 1.0f);
                }
            }
        }
    }
}

extern "C" void kernel_launch(void* const* d_in, const int* in_sizes, int n_in,
                              void* d_out, int out_size, void* d_ws, size_t ws_size,
                              hipStream_t stream) {
    const float* x    = (const float*)d_in[0];
    const float* ln_w = (const float*)d_in[1];
    const float* ln_b = (const float*)d_in[2];
    const float* sw   = (const float*)d_in[3];
    const float* sb   = (const float*)d_in[4];
    const float* dw   = (const float*)d_in[5];
    float* out = (float*)d_out;

    float* wsf = (float*)d_ws;
    float* rowsum = wsf;                               // 256 f32
    float* cvec   = rowsum + OPAD;                     // 256 f32
    unsigned short* Wfh = (unsigned short*)(cvec + OPAD);   // 256*224 u16
    unsigned short* Wfl = Wfh + OPAD * (KQ * 32);           // 256*224 u16
    char* after = (char*)(Wfl + OPAD * (KQ * 32));          // byte 231,424

    const size_t bpk_elems = (size_t)B_ * NKO * D_ * 8;     // 11,010,048
    const size_t need = (size_t)(after - (char*)d_ws) + 2 * bpk_elems * sizeof(unsigned short);

    prep_w_kernel<<<OPAD, 256, 0, stream>>>(sw, sb, dw, Wfh, Wfl, rowsum, cvec);

    if (ws_size >= need) {
        unsigned short* Bh = (unsigned short*)after;
        unsigned short* Bl = Bh + bpk_elems;
        ln_split_kernel<<<dim3(NKO, B_), 512, 0, stream>>>(x, ln_w, Bh, Bl);
        gemm_bpk_kernel<<<dim3(12, B_), 512, 0, stream>>>(
            x, ln_b, Wfh, Wfl, Bh, Bl, rowsum, cvec, out);
    } else {
        float* mu   = (float*)after;       // 12544+pad
        float* rstd = mu + 12608;
        ln_stats_kernel<<<(B_ * N_) / 4, 256, 0, stream>>>(x, mu, rstd);
        gemm_lds_kernel<<<dim3(12, B_), 512, 0, stream>>>(
            x, ln_w, ln_b, Wfh, Wfl, rowsum, cvec, mu, rstd, out);
    }
}